// Round 3
// baseline (393.282 us; speedup 1.0000x reference)
//
#include <hip/hip_runtime.h>
#include <hip/hip_bf16.h>

// QuantizedSimpleSSM — round 8: occupancy-by-grid fix. Per-CU model: 256 VALU
// issue cyc/k-step, ~192 LDS cyc (broadcast-aware), yet 518 cyc elapsed -> the
// gap is latency not covered by only 2 blocks/CU, and 2/CU is a GRID limit
// (512 blocks / 256 CU) while VGPR=128 + LDS 32KB allow 4/CU. gemm_R and the
// D-pass of gemm_Y are independent of recur -> merge into one 1024-block
// kernel (4/CU co-resident, launch_bounds(256,4) pins VGPR<=128). D-pass
// writes raw acc into Y (d_out as scratch); gemm_YC fuses q8(accC + pd) in its
// epilogue — bitwise identical (pd is the same fp32 chain value, exact through
// memory). quantk folded into quantT3. BK=32 gemm_pass unchanged from R7.
// Numerics contract (absmax 0.0 since R2): every output element is one fp32
// FMA chain in strictly ascending k; recurrence mul-then-add + q8.

#define DINX 512
#define LSEQ 512
#define NDIM 512

__device__ __forceinline__ float q8(float x) {
    float xa = fabsf(x);
    float w  = __fadd_rn(xa, 1e-8f);
    int e = (int)((__float_as_uint(w) >> 23) & 0xFFu) - 127;   // floor(log2(w))
    e = e < -7 ? -7 : (e > 7 ? 7 : e);
    float p    = __int_as_float((unsigned)((e + 127) << 23));   // exact 2^e
    float invp = __int_as_float((unsigned)((127 - e) << 23));   // exact 2^-e
    float t  = __fmul_rn(__fsub_rn(__fmul_rn(xa, invp), 1.0f), 8.0f);
    float m  = __fmul_rn(rintf(t), 0.125f);                     // half-to-even
    float r  = __fmul_rn(__fadd_rn(1.0f, m), p);
    return copysignf(r, x);
}

// out[c][r] = q8(in[r][c]) for three 512x512 matrices; block (0,0,0) also
// quants the A vector. grid (16,16,3), block 256.
__global__ __launch_bounds__(256) void quantT3A(const float* __restrict__ B,
                                                const float* __restrict__ C,
                                                const float* __restrict__ D,
                                                const float* __restrict__ A,
                                                float* __restrict__ Bqt,
                                                float* __restrict__ Cqt,
                                                float* __restrict__ Dqt,
                                                float* __restrict__ Aq) {
    __shared__ float tl[32][33];
    if (blockIdx.z == 0 && blockIdx.x == 0 && blockIdx.y == 0) {
        Aq[threadIdx.x]       = q8(A[threadIdx.x]);
        Aq[256 + threadIdx.x] = q8(A[256 + threadIdx.x]);
    }
    const float* in = blockIdx.z == 0 ? B : (blockIdx.z == 1 ? C : D);
    float* out      = blockIdx.z == 0 ? Bqt : (blockIdx.z == 1 ? Cqt : Dqt);
    const int r0 = blockIdx.y * 32, c0 = blockIdx.x * 32;
    const int x = threadIdx.x & 31, y = threadIdx.x >> 5;   // 32 x 8
#pragma unroll
    for (int i = 0; i < 32; i += 8)
        tl[y + i][x] = q8(in[(r0 + y + i) * 512 + c0 + x]);
    __syncthreads();
#pragma unroll
    for (int i = 0; i < 32; i += 8)
        out[(c0 + y + i) * 512 + r0 + x] = tl[x][y + i];
}

// acc[p][i][q][j] += sum_k X[k][m0 + p*64 + tx*4 + i] * W[k][n0 + q*64 + ty*4 + j],
// k strictly ascending. X, W are [KTOT][512] row-major.
// LDS: Xs/Ws [32][128], single-buffered, BK=32 per barrier pair. Fragments are
// 16-B chunks at 4-dword stride -> 2-way bank aliasing max (free); Ws reads
// broadcast within quarter-waves.
__device__ __forceinline__ void gemm_pass(const float* __restrict__ X,
                                          const float* __restrict__ W,
                                          int m0, int n0, int KTOT,
                                          float (&acc)[2][4][2][4],
                                          float (*Xs)[128], float (*Ws)[128],
                                          int tid) {
    const int tx = tid & 15, ty = tid >> 4;
    const int srow = tid >> 4, sseg4 = (tid & 15) * 4;   // 16 rows x 16 chunks
    const float* xp = X + (size_t)srow * 512 + m0 + sseg4;
    const float* wp = W + (size_t)srow * 512 + n0 + sseg4;
    for (int k0 = 0; k0 < KTOT; k0 += 32) {
        // stage rows srow and srow+16 of the 32-row tile, both halves (0/64)
        float4 x0 = *(const float4*)xp;
        float4 x1 = *(const float4*)(xp + 64);
        float4 x2 = *(const float4*)(xp + 16 * 512);
        float4 x3 = *(const float4*)(xp + 16 * 512 + 64);
        float4 w0 = *(const float4*)wp;
        float4 w1 = *(const float4*)(wp + 64);
        float4 w2 = *(const float4*)(wp + 16 * 512);
        float4 w3 = *(const float4*)(wp + 16 * 512 + 64);
        xp += 32 * 512; wp += 32 * 512;
        __syncthreads();                 // prev-tile reads done before overwrite
        *(float4*)&Xs[srow][sseg4]           = x0;
        *(float4*)&Xs[srow][64 + sseg4]      = x1;
        *(float4*)&Xs[16 + srow][sseg4]      = x2;
        *(float4*)&Xs[16 + srow][64 + sseg4] = x3;
        *(float4*)&Ws[srow][sseg4]           = w0;
        *(float4*)&Ws[srow][64 + sseg4]      = w1;
        *(float4*)&Ws[16 + srow][sseg4]      = w2;
        *(float4*)&Ws[16 + srow][64 + sseg4] = w3;
        __syncthreads();
#pragma unroll
        for (int k = 0; k < 32; ++k) {
            float a[2][4], b[2][4];
            *(float4*)&a[0][0] = *(const float4*)&Xs[k][tx * 4];
            *(float4*)&a[1][0] = *(const float4*)&Xs[k][64 + tx * 4];
            *(float4*)&b[0][0] = *(const float4*)&Ws[k][ty * 4];
            *(float4*)&b[1][0] = *(const float4*)&Ws[k][64 + ty * 4];
#pragma unroll
            for (int p = 0; p < 2; ++p)
#pragma unroll
                for (int i = 0; i < 4; ++i)
#pragma unroll
                    for (int q = 0; q < 2; ++q)
#pragma unroll
                        for (int j = 0; j < 4; ++j)
                            acc[p][i][q][j] = fmaf(a[p][i], b[q][j], acc[p][i][q][j]);
        }
    }
}

// Fused R + Y_D kernel. grid (4,4,64), block 256, 4 blocks/CU co-resident.
// z<32:  R[b][t][n] = sum_d u[b][d][t] * Bqt[d][n]           (raw)
// z>=32: Pd[b][o][t] = sum_d u[b][d][t] * Dqt[d][o]          (raw, into Y buf)
__global__ __launch_bounds__(256, 4) void gemm_RD(const float* __restrict__ u,
                                                  const float* __restrict__ Bqt,
                                                  const float* __restrict__ Dqt,
                                                  float* __restrict__ R,
                                                  float* __restrict__ Pd) {
    __shared__ float Xs[32][128];
    __shared__ float Ws[32][128];
    const int zz = blockIdx.z;
    const int b  = zz & 31;
    const bool isR = zz < 32;
    const int t0 = blockIdx.x * 128, n0 = blockIdx.y * 128;
    const int tid = threadIdx.x;
    const int tx = tid & 15, ty = tid >> 4;
    const float* ub = u + (size_t)b * (DINX * LSEQ);
    const float* Wm = isR ? Bqt : Dqt;
    float acc[2][4][2][4] = {};
    gemm_pass(ub, Wm, t0, n0, DINX, acc, Xs, Ws, tid);
    if (isR) {
        float* Rb = R + (size_t)b * (LSEQ * NDIM);
#pragma unroll
        for (int p = 0; p < 2; ++p)
#pragma unroll
            for (int i = 0; i < 4; ++i) {
                float* row = Rb + (size_t)(t0 + p * 64 + tx * 4 + i) * NDIM + n0;
                *(float4*)(row + ty * 4)      = make_float4(acc[p][i][0][0], acc[p][i][0][1],
                                                            acc[p][i][0][2], acc[p][i][0][3]);
                *(float4*)(row + 64 + ty * 4) = make_float4(acc[p][i][1][0], acc[p][i][1][1],
                                                            acc[p][i][1][2], acc[p][i][1][3]);
            }
    } else {
        float* Yb = Pd + (size_t)b * (NDIM * LSEQ);
#pragma unroll
        for (int q = 0; q < 2; ++q)
#pragma unroll
            for (int j = 0; j < 4; ++j) {
                float* row = Yb + (size_t)(n0 + q * 64 + ty * 4 + j) * LSEQ + t0;
                *(float4*)(row + tx * 4)      = make_float4(acc[0][0][q][j], acc[0][1][q][j],
                                                            acc[0][2][q][j], acc[0][3][q][j]);
                *(float4*)(row + 64 + tx * 4) = make_float4(acc[1][0][q][j], acc[1][1][q][j],
                                                            acc[1][2][q][j], acc[1][3][q][j]);
            }
    }
}

// Per-(b, n-chunk) recurrence (bitwise np: mul-then-add, q8). Writes S[b][n][t].
// grid (32, 8), block 64 -> 256 blocks, one chain-wave per CU.
__global__ __launch_bounds__(64) void recur(const float* __restrict__ R,
                                            const float* __restrict__ Aq,
                                            float* __restrict__ S) {
    __shared__ float tile[16][68];
    const int b  = blockIdx.x;
    const int n0 = blockIdx.y * 64;
    const int n  = threadIdx.x;                 // 0..63
    const float a = Aq[n0 + n];
    const float* Rb = R + (size_t)b * (LSEQ * NDIM) + n0;
    float* Sb = S + (size_t)b * (NDIM * LSEQ) + (size_t)n0 * LSEQ;
    float s = 0.0f;
    const int c = (n & 3) * 4;
    const int rbase = n >> 2;                   // 0..15
    for (int t0 = 0; t0 < LSEQ; t0 += 16) {
#pragma unroll
        for (int tt = 0; tt < 16; ++tt) {
            float r = Rb[(size_t)(t0 + tt) * NDIM + n];
            s = q8(__fadd_rn(__fmul_rn(s, a), r));
            tile[tt][n] = s;
        }
        __syncthreads();
#pragma unroll
        for (int p = 0; p < 4; ++p) {
            int row = p * 16 + rbase;
            float4 v = make_float4(tile[c + 0][row], tile[c + 1][row],
                                   tile[c + 2][row], tile[c + 3][row]);
            *(float4*)(Sb + (size_t)row * LSEQ + t0 + c) = v;
        }
        __syncthreads();
    }
}

// Y[b][o][t] = q8( (sum_n S[n][t]*Cqt[n][o]) + Pd[b][o][t] ), Pd staged in Y.
// grid (4,4,32), block 256.
__global__ __launch_bounds__(256) void gemm_YC(const float* __restrict__ S,
                                               const float* __restrict__ Cqt,
                                               float* __restrict__ Y) {
    __shared__ float Xs[32][128];
    __shared__ float Ws[32][128];
    const int b  = blockIdx.z;
    const int t0 = blockIdx.x * 128, o0 = blockIdx.y * 128;
    const int tid = threadIdx.x;
    const int tx = tid & 15, ty = tid >> 4;
    const float* Sb = S + (size_t)b * (NDIM * LSEQ);
    float acc[2][4][2][4] = {};
    gemm_pass(Sb, Cqt, t0, o0, NDIM, acc, Xs, Ws, tid);

    float* Yb = Y + (size_t)b * (NDIM * LSEQ);
#pragma unroll
    for (int q = 0; q < 2; ++q)
#pragma unroll
        for (int j = 0; j < 4; ++j) {
            float* row = Yb + (size_t)(o0 + q * 64 + ty * 4 + j) * LSEQ + t0;
            float4 v0 = *(const float4*)(row + tx * 4);
            float4 v1 = *(const float4*)(row + 64 + tx * 4);
            *(float4*)(row + tx * 4) =
                make_float4(q8(__fadd_rn(acc[0][0][q][j], v0.x)),
                            q8(__fadd_rn(acc[0][1][q][j], v0.y)),
                            q8(__fadd_rn(acc[0][2][q][j], v0.z)),
                            q8(__fadd_rn(acc[0][3][q][j], v0.w)));
            *(float4*)(row + 64 + tx * 4) =
                make_float4(q8(__fadd_rn(acc[1][0][q][j], v1.x)),
                            q8(__fadd_rn(acc[1][1][q][j], v1.y)),
                            q8(__fadd_rn(acc[1][2][q][j], v1.z)),
                            q8(__fadd_rn(acc[1][3][q][j], v1.w)));
        }
}

extern "C" void kernel_launch(void* const* d_in, const int* in_sizes, int n_in,
                              void* d_out, int out_size, void* d_ws, size_t ws_size,
                              hipStream_t stream) {
    const float* u = (const float*)d_in[0];   // (32, 512, 512)
    const float* A = (const float*)d_in[1];   // (512,)
    const float* B = (const float*)d_in[2];   // (512, 512)
    const float* C = (const float*)d_in[3];   // (512, 512)
    const float* D = (const float*)d_in[4];   // (512, 512)

    float* ws  = (float*)d_ws;
    float* Aq  = ws;                    // 512
    float* Bqt = Aq + 512;              // 262144  [d][n]
    float* Cqt = Bqt + 262144;          // 262144  [n][o]
    float* Dqt = Cqt + 262144;          // 262144  [d][o]
    float* R   = Dqt + 262144;          // 8388608 [b][t][n]
    float* S   = R + 8388608;           // 8388608 [b][n][t]
    float* Y   = (float*)d_out;         // 8388608 [b][o][t] (also Pd scratch)

    quantT3A<<<dim3(16, 16, 3), 256, 0, stream>>>(B, C, D, A, Bqt, Cqt, Dqt, Aq);
    gemm_RD<<<dim3(4, 4, 64), 256, 0, stream>>>(u, Bqt, Dqt, R, Y);
    recur<<<dim3(32, 8), 64, 0, stream>>>(R, Aq, S);
    gemm_YC<<<dim3(4, 4, 32), 256, 0, stream>>>(S, Cqt, Y);
}